// Round 3
// baseline (269.159 us; speedup 1.0000x reference)
//
#include <hip/hip_runtime.h>
#include <hip/hip_bf16.h>
#include <math.h>

#define EMB 1024
#define BATCH 32
#define SEQ 1024
#define J2 256          // 2*PROJ
#define BM 64
#define BN 256
#define BK 64
#define NIT (EMB / BK)  // 16 K-steps
#define PSEL 0x07060302u   // v_perm selector: [f1.hi16 : f0.hi16]

typedef __attribute__((ext_vector_type(8))) short short8;
typedef __attribute__((ext_vector_type(4))) float f32x4;
typedef const __attribute__((address_space(1))) void gvoid;
typedef __attribute__((address_space(3))) void lvoid;

__device__ __forceinline__ unsigned bcast(float f) {
    union { float f; unsigned u; } c; c.f = f; return c.u;
}
// pack two fp32 -> two bf16 (round-half-up) in one u32: f0 low, f1 high
__device__ __forceinline__ unsigned pack_bf16(float f0, float f1) {
    return __builtin_amdgcn_perm(bcast(f1) + 0x8000u, bcast(f0) + 0x8000u, PSEL);
}

// ---------------- Kernel 0: convert W fp32 -> bf16 -------------------------
__global__ __launch_bounds__(256) void convw(const float* __restrict__ W,
                                             __hip_bfloat16* __restrict__ Wb) {
    int i = blockIdx.x * 256 + threadIdx.x;          // 0 .. 65535, 4 floats each
    float4 v = ((const float4*)W)[i];
    __hip_bfloat16 h[4];
    h[0] = __float2bfloat16(v.x); h[1] = __float2bfloat16(v.y);
    h[2] = __float2bfloat16(v.z); h[3] = __float2bfloat16(v.w);
    *(short4*)&Wb[i * 4] = *(short4*)h;
}

// ---------------- Kernel 1: qk = ctx @ W^T + bias (bf16 MFMA) --------------
// Double-buffered LDS (80KB, 2 blocks/CU), XOR-swizzled (slot ^= row&7, 16B
// slots), one barrier per K-step. This round: full-iteration-distance A
// prefetch + counted vmcnt drain.
// Per iteration it:
//   1. issue 8x global_load_lds B(it+1) -> Bn
//   2. sched_barrier(0)   [pin issue order: gll BEFORE ctx loads, so the
//                          counted vmcnt(4) below implies "all gll done"]
//   3. pack ctx(it+1) (regs loaded one full iteration ago) -> ds_write An
//   4. issue ctx(it+2) -> regs (4 VMEM, newest in queue)
//   5. compute tile it (ds_read + MFMA)
//   6. s_waitcnt vmcnt(4) lgkmcnt(0)   [gll+ds_write published; ctx flies]
//   7. s_barrier
__global__ __launch_bounds__(256) void gemm_mfma(const float* __restrict__ ctx,
                                                 const __hip_bfloat16* __restrict__ Wb,
                                                 const float* __restrict__ bias,
                                                 __hip_bfloat16* __restrict__ qkb) {
    __shared__ __align__(16) __hip_bfloat16 As[2 * BM * BK];   // 16 KB
    __shared__ __align__(16) __hip_bfloat16 Bs[2 * BN * BK];   // 64 KB
    const int t = threadIdx.x;
    const int lane = t & 63, w = t >> 6;
    const int m0 = blockIdx.x * BM;
    const int wn = w * 64;
    const int lm = lane & 15, lq = lane >> 4;

    f32x4 acc[4][4] = {};

    float bv[4];
    #pragma unroll
    for (int ni = 0; ni < 4; ni++) bv[ni] = bias[wn + ni * 16 + lm];

    const float4* ctx4 = (const float4*)ctx;
    // per-thread A staging coords (2 chunks of 16B per thread per K-step)
    const int ar0 = t >> 3, ak = t & 7;
    const int ar1 = 32 + ar0;
    const int as0 = (ak ^ (ar0 & 7)) * 8;     // swizzled LDS slot (elements)
    const int as1 = (ak ^ (ar1 & 7)) * 8;
    const size_t abase0 = (size_t)(m0 + ar0) * 256 + ak * 2;
    const size_t abase1 = (size_t)(m0 + ar1) * 256 + ak * 2;

    // ---- prologue ---------------------------------------------------------
    // gll B(0) -> buf0
    #pragma unroll
    for (int c = 0; c < 8; c++) {
        int li = c * 256 + t, row = li >> 3;
        int k8 = (li & 7) ^ (row & 7);        // pre-swizzled global source
        __builtin_amdgcn_global_load_lds(
            (gvoid*)(Wb + (size_t)row * EMB + k8 * 8),
            (lvoid*)&Bs[(c * 256 + w * 64) * 8], 16, 0, 0);
    }
    __builtin_amdgcn_sched_barrier(0);
    // ctx(0) -> regs, pack -> As buf0 (one-time full-latency stall)
    float4 v0a = ctx4[abase0], v0b = ctx4[abase0 + 1];
    float4 v1a = ctx4[abase1], v1b = ctx4[abase1 + 1];
    {
        uint4 p0, p1;
        p0.x = pack_bf16(v0a.x, v0a.y); p0.y = pack_bf16(v0a.z, v0a.w);
        p0.z = pack_bf16(v0b.x, v0b.y); p0.w = pack_bf16(v0b.z, v0b.w);
        p1.x = pack_bf16(v1a.x, v1a.y); p1.y = pack_bf16(v1a.z, v1a.w);
        p1.z = pack_bf16(v1b.x, v1b.y); p1.w = pack_bf16(v1b.z, v1b.w);
        *(uint4*)&As[ar0 * BK + as0] = p0;
        *(uint4*)&As[ar1 * BK + as1] = p1;
    }
    __builtin_amdgcn_sched_barrier(0);
    // ctx(1) -> regs (stays in flight across the prologue drain)
    v0a = ctx4[abase0 + 16]; v0b = ctx4[abase0 + 17];
    v1a = ctx4[abase1 + 16]; v1b = ctx4[abase1 + 17];
    asm volatile("s_waitcnt vmcnt(4) lgkmcnt(0)" ::: "memory");
    __builtin_amdgcn_s_barrier();

    // ---- main loop: one barrier per K-step --------------------------------
    for (int it = 0; it < NIT; ++it) {
        const int cur = it & 1;
        const __hip_bfloat16* Ac = As + cur * (BM * BK);
        const __hip_bfloat16* Bc = Bs + cur * (BN * BK);
        __hip_bfloat16* An = As + (cur ^ 1) * (BM * BK);
        __hip_bfloat16* Bn = Bs + (cur ^ 1) * (BN * BK);
        const bool stage = (it + 1 < NIT);
        const bool pre   = (it + 2 < NIT);
        if (stage) {
            // B loads for it+1 -> LDS buffer cur^1 (in flight during compute)
            const int k0n = (it + 1) * BK;
            #pragma unroll
            for (int c = 0; c < 8; c++) {
                int li = c * 256 + t, row = li >> 3;
                int k8 = (li & 7) ^ (row & 7);
                __builtin_amdgcn_global_load_lds(
                    (gvoid*)(Wb + (size_t)row * EMB + k0n + k8 * 8),
                    (lvoid*)&Bn[(c * 256 + w * 64) * 8], 16, 0, 0);
            }
            __builtin_amdgcn_sched_barrier(0);
            // pack ctx(it+1) (loaded one iteration ago) -> An
            uint4 p0, p1;
            p0.x = pack_bf16(v0a.x, v0a.y); p0.y = pack_bf16(v0a.z, v0a.w);
            p0.z = pack_bf16(v0b.x, v0b.y); p0.w = pack_bf16(v0b.z, v0b.w);
            p1.x = pack_bf16(v1a.x, v1a.y); p1.y = pack_bf16(v1a.z, v1a.w);
            p1.z = pack_bf16(v1b.x, v1b.y); p1.w = pack_bf16(v1b.z, v1b.w);
            *(uint4*)&An[ar0 * BK + as0] = p0;
            *(uint4*)&An[ar1 * BK + as1] = p1;
            if (pre) {
                // issue ctx(it+2) -> regs (4 newest VMEM ops)
                const size_t ko = (size_t)(it + 2) * (BK / 4);
                v0a = ctx4[abase0 + ko]; v0b = ctx4[abase0 + ko + 1];
                v1a = ctx4[abase1 + ko]; v1b = ctx4[abase1 + ko + 1];
            }
        }
        // ---- compute tile it from buffer cur ------------------------------
        #pragma unroll
        for (int kk = 0; kk < BK; kk += 32) {
            const int off = ((((kk >> 5) << 2) + lq) ^ (lm & 7)) * 8;
            short8 af[4], bfr[4];
            #pragma unroll
            for (int i = 0; i < 4; i++) {
                af[i]  = *(const short8*)&Ac[(i * 16 + lm) * BK + off];
                bfr[i] = *(const short8*)&Bc[(wn + i * 16 + lm) * BK + off];
            }
            #pragma unroll
            for (int mi = 0; mi < 4; mi++)
                #pragma unroll
                for (int ni = 0; ni < 4; ni++)
                    acc[mi][ni] = __builtin_amdgcn_mfma_f32_16x16x32_bf16(
                        af[mi], bfr[ni], acc[mi][ni], 0, 0, 0);
        }
        if (stage) {
            if (pre)
                asm volatile("s_waitcnt vmcnt(4) lgkmcnt(0)" ::: "memory");
            else
                asm volatile("s_waitcnt vmcnt(0) lgkmcnt(0)" ::: "memory");
            __builtin_amdgcn_s_barrier();
        }
        // it == NIT-1: no barrier needed; epilogue touches no LDS
    }

    // ---- epilogue: D row = m (A row), col = n; add bias, store bf16 -------
    #pragma unroll
    for (int mi = 0; mi < 4; mi++) {
        #pragma unroll
        for (int r = 0; r < 4; r++) {
            int m = m0 + mi * 16 + lq * 4 + r;
            int s = m >> 5, b = m & 31;
            __hip_bfloat16* orow = qkb + (size_t)((b << 10) + s) * J2;
            #pragma unroll
            for (int ni = 0; ni < 4; ni++) {
                int n = wn + ni * 16 + lm;
                orow[n] = __float2bfloat16(acc[mi][ni][r] + bv[ni]);
            }
        }
    }
}

// ---------------- Kernel 2: neighbor dot products (bf16 qk) ----------------
// fwd[b,s] = q[b,s].k[b,s+1]/EMB ; bwd[b,s] = q[b,s+1].k[b,s]/EMB (s<S-1)
__global__ __launch_bounds__(256) void scores(const __hip_bfloat16* __restrict__ qkb,
                                              float* __restrict__ fwd,
                                              float* __restrict__ bwd) {
    int wave = threadIdx.x >> 6, lane = threadIdx.x & 63;
    int idx = blockIdx.x * 4 + wave;       // idx = b*SEQ + s
    int s = idx & (SEQ - 1);
    if (s == SEQ - 1) return;
    const unsigned* r0 = (const unsigned*)(qkb + (size_t)idx * J2);
    const unsigned* r1 = r0 + 128;         // next row (s+1), in u32 units
    unsigned q0 = r0[lane], k0 = r0[64 + lane];
    unsigned q1 = r1[lane], k1 = r1[64 + lane];
    float2 q0f = __bfloat1622float2(*(const __hip_bfloat162*)&q0);
    float2 k0f = __bfloat1622float2(*(const __hip_bfloat162*)&k0);
    float2 q1f = __bfloat1622float2(*(const __hip_bfloat162*)&q1);
    float2 k1f = __bfloat1622float2(*(const __hip_bfloat162*)&k1);
    float f = q0f.x * k1f.x + q0f.y * k1f.y;   // q[s] . k[s+1]
    float w = q1f.x * k0f.x + q1f.y * k0f.y;   // q[s+1] . k[s]
    #pragma unroll
    for (int off = 32; off; off >>= 1) {
        f += __shfl_xor(f, off);
        w += __shfl_xor(w, off);
    }
    if (lane == 0) {
        fwd[idx] = f * (1.f / 1024.f);
        bwd[idx] = w * (1.f / 1024.f);
    }
}

// ---------------- Kernel 3: softmax, neighbor_attn, log, prefix-sum --------
__global__ __launch_bounds__(1024) void neighbor(const float* __restrict__ fwd,
                                                 const float* __restrict__ bwd,
                                                 const float* __restrict__ prior,
                                                 const int* __restrict__ mask,
                                                 float* __restrict__ out_n,
                                                 float* __restrict__ csp) {
    int b = blockIdx.x, s = threadIdx.x;
    int lane = s & 63, w = s >> 6;          // 16 waves
    __shared__ float p1s[SEQ];
    __shared__ float incl[SEQ];
    __shared__ float wsum[16];
    int base = b << 10;
    int rolled = mask[base + ((s + 1) & (SEQ - 1))];
    float c0 = (s < SEQ - 1) ? fwd[base + s] : -INFINITY;
    if (rolled) c0 = -INFINITY;
    float c1 = (s > 0) ? bwd[base + s - 1] : -INFINITY;
    float m = fmaxf(c0, c1);
    float e0 = expf(c0 - m), e1 = expf(c1 - m);
    float inv = 1.f / (e0 + e1);
    float p0 = e0 * inv, p1 = e1 * inv;
    p1s[s] = p1;
    __syncthreads();
    float shift = (s < SEQ - 1) ? p1s[s + 1] : 0.f;   // flattened roll: next-batch p1[0]==0
    float p = sqrtf(p0 * shift + 1e-6f);
    float pr = prior[base + s];
    float na = pr + (1.f - pr) * p;
    out_n[base + s] = na;
    float lp = logf(na);
    if (rolled) lp = 0.f;
    // wave-level inclusive scan (6 shuffle steps, no barriers)
    float x = lp;
    #pragma unroll
    for (int off = 1; off < 64; off <<= 1) {
        float v = __shfl_up(x, off);
        if (lane >= off) x += v;
    }
    if (lane == 63) wsum[w] = x;
    __syncthreads();
    if (w == 0) {
        float v = (lane < 16) ? wsum[lane] : 0.f;
        #pragma unroll
        for (int off = 1; off < 16; off <<= 1) {
            float t2 = __shfl_up(v, off);
            if (lane >= off) v += t2;
        }
        if (lane < 16) wsum[lane] = v;
    }
    __syncthreads();
    float woff = (w > 0) ? wsum[w - 1] : 0.f;
    incl[s] = x + woff;
    __syncthreads();
    csp[base + s] = (s == 0) ? 0.f : incl[s - 1];   // exclusive prefix sum
}

// ---------------- Kernel 4: constituent_attn ------------------------------
// 8 output rows per block: csp row (cj, float4/thread) loaded once and held
// in registers across rows; fast exp (v_exp_f32).
__global__ __launch_bounds__(256) void outk(const float* __restrict__ csp,
                                            float* __restrict__ out) {
    int blk = blockIdx.x;                    // b*128 + i0/8
    int b = blk >> 7, i0 = (blk & 127) << 3;
    const float* crow = csp + (b << 10);
    int t = threadIdx.x;
    float4 cj = ((const float4*)crow)[t];
    int j0 = t << 2;
    float4* o4 = (float4*)(out + ((size_t)(b << 10) + i0) * SEQ) + t;
    #pragma unroll
    for (int r = 0; r < 8; r++) {
        int i = i0 + r;
        float ci = crow[i];                  // uniform -> scalar load
        float4 v; float d;
        d = (j0 + 0 > i) ? cj.x - ci : ci - cj.x;
        v.x = (j0 + 0 == i) ? 0.f : __expf(d);
        d = (j0 + 1 > i) ? cj.y - ci : ci - cj.y;
        v.y = (j0 + 1 == i) ? 0.f : __expf(d);
        d = (j0 + 2 > i) ? cj.z - ci : ci - cj.z;
        v.z = (j0 + 2 == i) ? 0.f : __expf(d);
        d = (j0 + 3 > i) ? cj.w - ci : ci - cj.w;
        v.w = (j0 + 3 == i) ? 0.f : __expf(d);
        o4[r * 256] = v;
    }
}

extern "C" void kernel_launch(void* const* d_in, const int* in_sizes, int n_in,
                              void* d_out, int out_size, void* d_ws, size_t ws_size,
                              hipStream_t stream) {
    (void)in_sizes; (void)n_in; (void)out_size; (void)ws_size;
    const float* ctx   = (const float*)d_in[0];   // [S, B, E]
    const float* prior = (const float*)d_in[1];   // [B, S]
    const int*   mask  = (const int*)d_in[2];     // [B, S]
    const float* W     = (const float*)d_in[3];   // [256, 1024]
    const float* bias  = (const float*)d_in[4];   // [256]
    float* out = (float*)d_out;
    float* ws  = (float*)d_ws;

    __hip_bfloat16* qkb = (__hip_bfloat16*)ws;    // B*S*256 bf16 = 16.7 MB
    float* fwd = ws + 4194304;
    float* bwd = fwd + 32768;
    float* csp = bwd + 32768;
    __hip_bfloat16* Wb = (__hip_bfloat16*)(csp + 32768);   // 256*1024 bf16
    float* out_n = out + (size_t)BATCH * SEQ * SEQ;

    convw    <<<256, 256, 0, stream>>>(W, Wb);
    gemm_mfma<<<(BATCH * SEQ) / BM, 256, 0, stream>>>(ctx, Wb, bias, qkb);
    scores   <<<(BATCH * SEQ) / 4, 256, 0, stream>>>(qkb, fwd, bwd);
    neighbor <<<BATCH, 1024, 0, stream>>>(fwd, bwd, prior, mask, out_n, csp);
    outk     <<<(BATCH * SEQ) / 8, 256, 0, stream>>>(csp, out);
}